// Round 6
// baseline (986.007 us; speedup 1.0000x reference)
//
#include <hip/hip_runtime.h>
#include <cstdint>
#include <cstddef>

// Problem constants (fp32 in / fp32 out; bf16 internal compute, 2% tolerance)
#define Bsz 8
#define Ssz 1024
#define Esz 1024
#define Hn  16
#define Dh  64
#define OUT_PROBS 8388608
#define OUT_MODE  8388616
#define OUT_MEAN  8388624

typedef unsigned short u16;
typedef __attribute__((ext_vector_type(8)))  __bf16 bf16x8;
typedef __attribute__((ext_vector_type(4)))  float  floatx4;
typedef __attribute__((ext_vector_type(16))) float  floatx16;

__device__ __forceinline__ float bf2f(u16 u){ return __uint_as_float(((unsigned)u)<<16); }
__device__ __forceinline__ u16 f2bf(float f){
  unsigned u = __float_as_uint(f);
  u += 0x7fffu + ((u>>16)&1u);            // RNE
  return (u16)(u>>16);
}
__device__ __forceinline__ void unpack2(unsigned u, float& lo, float& hi){
  lo = __uint_as_float(u<<16);
  hi = __uint_as_float(u & 0xffff0000u);
}
__device__ __forceinline__ unsigned pack2(float lo, float hi){
  return (unsigned)f2bf(lo) | ((unsigned)f2bf(hi)<<16);
}
__device__ __forceinline__ void async16(const void* g, void* l){
  __builtin_amdgcn_global_load_lds((const __attribute__((address_space(1))) void*)g,
                                   (__attribute__((address_space(3))) void*)l, 16, 0, 0);
}
// tanh-form gelu: |err vs exact erf-gelu| <~1e-3, ~9 VALU inst (vs erff ~20)
__device__ __forceinline__ float gelu_fast(float x){
  const float x2 = x*x;
  const float y  = x * fmaf(0.0356774081f, x2, 0.7978845608f);  // sqrt(2/pi)*(x+0.044715x^3)
  const float e  = __expf(2.0f*y);
  const float t  = 1.0f - 2.0f/(e + 1.0f);                      // tanh(y)
  const float h  = 0.5f*x;
  return fmaf(h, t, h);
}

// ---------------------------------------------------------------------------
// fp32 -> bf16 conversion, all six tensors in one launch (8 elems/thread)
// ---------------------------------------------------------------------------
struct F2B {
  const float* s[6];
  u16* d[6];
  unsigned end[6];   // cumulative region ends, 8-elem units
};

__global__ __launch_bounds__(256)
void f2b_multi(F2B p)
{
  const unsigned i = blockIdx.x*256 + threadIdx.x;
  int k = 0;
  #pragma unroll
  for(int t=0; t<5; t++) if(i >= p.end[t]) k = t+1;
  const unsigned j = i - (k ? p.end[k-1] : 0);
  float4 a = ((const float4*)p.s[k])[2*j];
  float4 b = ((const float4*)p.s[k])[2*j+1];
  uint4 w;
  w.x = pack2(a.x, a.y); w.y = pack2(a.z, a.w);
  w.z = pack2(b.x, b.y); w.w = pack2(b.z, b.w);
  ((uint4*)p.d[k])[j] = w;
}

// ---------------------------------------------------------------------------
// GEMM: C[M,N] = A[M,K] @ W[N,K]^T, bf16 in, fp32 accum.
// BK=64 K-loop (two 128x32 LDS buffers/operand, 64B row stride), inner math
// now mfma_f32_32x32x16_bf16: 2x2 32-tiles per wave = 16 mfma/BK64 (was 32),
// ~17% better mfma-pipe rate (m119) and half the issue slots.
// A/B frag: m=lane&31, k=(lane>>5)*8+j. C/D: col=lane&31,
// row=(r&3)+8*(r>>2)+4*(lane>>5) (m74/m101-verified).
// EPI: 0 plain bf16; 1 bf16 + residual(bf16 R); 2 bf16 gelu; 3 f32 gelu
// SKIP: 1 = run only where modes[batch]!=0 (thinking); 2 = only modes==0 (fast)
// ---------------------------------------------------------------------------
template<int EPI, int SKIP>
__global__ __launch_bounds__(256, 2)
void gemm_bt(const u16* __restrict__ A, const u16* __restrict__ W,
             void* __restrict__ Cv, const u16* __restrict__ R,
             const float* __restrict__ modes, int N, int K)
{
  const int m0 = blockIdx.x * 128;
  if(SKIP == 1 && modes[m0 >> 10] == 0.0f) return;
  if(SKIP == 2 && modes[m0 >> 10] != 0.0f) return;

  __shared__ __align__(16) u16 AsLo[128*32];
  __shared__ __align__(16) u16 AsHi[128*32];
  __shared__ __align__(16) u16 BsLo[128*32];
  __shared__ __align__(16) u16 BsHi[128*32];

  const int tid  = threadIdx.x;
  const int wave = tid >> 6;
  const int lane = tid & 63;
  const int l31  = lane & 31;
  const int hw   = lane >> 5;
  const int wm   = (wave >> 1) * 64;
  const int wn   = (wave & 1) * 64;
  const int n0   = blockIdx.y * 128;

  floatx16 acc[2][2];
  #pragma unroll
  for(int i=0;i<2;i++)
    #pragma unroll
    for(int j=0;j<2;j++)
      #pragma unroll
      for(int r=0;r<16;r++) acc[i][j][r] = 0.f;

  const int row0 = tid >> 2;
  const int kc   = (tid & 3) * 8;

  const u16* pA0 = A + (size_t)(m0 + row0)*K + kc;
  const u16* pA1 = pA0 + (size_t)64*K;
  const u16* pB0 = W + (size_t)(n0 + row0)*K + kc;
  const u16* pB1 = pB0 + (size_t)64*K;

  for(int k0 = 0; k0 < K; k0 += 64, pA0 += 64, pA1 += 64, pB0 += 64, pB1 += 64){
    __syncthreads();
    async16(pA0,      AsLo + wave*512);
    async16(pA1,      AsLo + 2048 + wave*512);
    async16(pA0 + 32, AsHi + wave*512);
    async16(pA1 + 32, AsHi + 2048 + wave*512);
    async16(pB0,      BsLo + wave*512);
    async16(pB1,      BsLo + 2048 + wave*512);
    async16(pB0 + 32, BsHi + wave*512);
    async16(pB1 + 32, BsHi + 2048 + wave*512);
    __syncthreads();

    #pragma unroll
    for(int buf=0; buf<2; buf++){
      const u16* As = buf ? AsHi : AsLo;
      const u16* Bs = buf ? BsHi : BsLo;
      #pragma unroll
      for(int ks=0; ks<2; ks++){
        const int kb = ks*16 + hw*8;
        bf16x8 af[2], bfr[2];
        #pragma unroll
        for(int i=0;i<2;i++){
          af[i]  = *(const bf16x8*)&As[(wm + i*32 + l31)*32 + kb];
          bfr[i] = *(const bf16x8*)&Bs[(wn + i*32 + l31)*32 + kb];
        }
        #pragma unroll
        for(int i=0;i<2;i++)
          #pragma unroll
          for(int j=0;j<2;j++)
            acc[i][j] = __builtin_amdgcn_mfma_f32_32x32x16_bf16(af[i], bfr[j], acc[i][j], 0, 0, 0);
      }
    }
  }

  // epilogue: C/D col=lane&31, row=(r&3)+8*(r>>2)+4*hw (m74/m101-verified)
  #pragma unroll
  for(int i=0;i<2;i++){
    #pragma unroll
    for(int j=0;j<2;j++){
      const int col = n0 + wn + j*32 + l31;
      #pragma unroll
      for(int r=0;r<16;r++){
        const int row = m0 + wm + i*32 + (r&3) + 8*(r>>2) + 4*hw;
        float v = acc[i][j][r];
        const size_t idx = (size_t)row*N + col;
        if(EPI == 1) v += bf2f(R[idx]);
        if(EPI == 2 || EPI == 3) v = gelu_fast(v);
        if(EPI == 3) ((float*)Cv)[idx] = v;
        else         ((u16*)Cv)[idx] = f2bf(v);
      }
    }
  }
}

// ---------------------------------------------------------------------------
// MFMA flash attention, v2. Block = 4 waves = 64-query tile of one (b,h).
// 16 KV chunks of 64 keys (34 KB LDS -> 4 blocks/CU). Q fragments hoisted to
// registers. Vt word-stride 34 and Ps stride 72 chosen so all LDS writes are
// <=2-way bank-aliased (free, m136). Early-exit for mode=0 batches.
// ---------------------------------------------------------------------------
#define VSTR 68    // u16 stride of Vt row (34 words; 8*34 % 32 = 16 -> 2-way)
#define PSTR 72    // u16 stride of Ps row (36 words)
__global__ __launch_bounds__(256, 4)
void attn_kernel(const u16* __restrict__ qkv, u16* __restrict__ out,
                 const float* __restrict__ modes)
{
  const int bh = blockIdx.x & 127;
  const int b  = bh >> 4;
  if(modes[b] == 0.0f) return;

  __shared__ __align__(16) u16 Qs[2*64*32];    // [half][row][32]
  __shared__ __align__(16) u16 Ks[2*64*32];    // [half][row][32]
  __shared__ __align__(16) u16 Vt[64*VSTR];    // [d][k] packed words
  __shared__ __align__(16) u16 Ps[64*PSTR];    // [m][k]
  __shared__ float lsump[2][64];

  const int tid = threadIdx.x;
  const int w   = tid >> 6;
  const int lane= tid & 63;
  const int q   = lane >> 4;
  const int r16 = lane & 15;

  const int qt = blockIdx.x >> 7;
  const int h  = bh & 15;
  const int q0 = qt * 64;

  const u16* qbase = qkv + (size_t)(b*Ssz)*3072;

  const int sr = tid >> 2;          // staging row 0..63
  const int sc = (tid & 3) * 8;     // staging col offset

  // stage Q tile (64x64) -> [half][64][32]
  #pragma unroll
  for(int half=0; half<2; half++)
    async16(qbase + (size_t)(q0 + sr)*3072 + h*64 + half*32 + sc,
            &Qs[half*2048 + w*512]);
  __syncthreads();

  const int wm  = (w >> 1) * 32;   // query-row offset
  const int wnS = (w & 1) * 32;    // key-col offset in S
  const int wnO = (w & 1) * 32;    // d-col offset in O

  // hoist Q fragments (chunk-invariant)
  bf16x8 qf[2][2];
  #pragma unroll
  for(int half=0; half<2; half++)
    #pragma unroll
    for(int i=0;i<2;i++)
      qf[half][i] = *(const bf16x8*)&Qs[half*2048 + (wm + i*16 + r16)*32 + q*8];

  floatx4 acc_o[2][2];
  #pragma unroll
  for(int i=0;i<2;i++)
    #pragma unroll
    for(int j=0;j<2;j++){ floatx4 z={0.f,0.f,0.f,0.f}; acc_o[i][j]=z; }
  float ps[2][4] = {{0.f,0.f,0.f,0.f},{0.f,0.f,0.f,0.f}};

  const int kp = tid & 31;          // key-pair for Vt staging
  const int dg = tid >> 5;          // d-group 0..7

  for(int ck=0; ck<16; ck++){
    const int k0 = ck*64;
    __syncthreads();   // prior-chunk Ks/Vt/Ps reads complete
    // stage K (64x64) -> [half][64][32]
    #pragma unroll
    for(int half=0; half<2; half++)
      async16(qbase + (size_t)(k0 + sr)*3072 + 1024 + h*64 + half*32 + sc,
              &Ks[half*2048 + w*512]);
    // stage V transposed: Vt[d][k], keys packed in pairs per word
    {
      const uint4 va = *(const uint4*)(qbase + (size_t)(k0 + 2*kp    )*3072 + 2048 + h*64 + dg*8);
      const uint4 vb = *(const uint4*)(qbase + (size_t)(k0 + 2*kp + 1)*3072 + 2048 + h*64 + dg*8);
      unsigned wa[4] = {va.x,va.y,va.z,va.w};
      unsigned wb[4] = {vb.x,vb.y,vb.z,vb.w};
      unsigned* vt32 = (unsigned*)Vt;
      #pragma unroll
      for(int u=0; u<4; u++){
        const int d0 = dg*8 + 2*u;
        vt32[(size_t)d0*34 + kp]     = (wa[u] & 0xffffu) | (wb[u] << 16);
        vt32[(size_t)(d0+1)*34 + kp] = (wa[u] >> 16) | (wb[u] & 0xffff0000u);
      }
    }
    __syncthreads();

    // S = Q.K^T  (wave tile 32 q x 32 keys, K=64)
    floatx4 accS[2][2];
    #pragma unroll
    for(int i=0;i<2;i++)
      #pragma unroll
      for(int j=0;j<2;j++){ floatx4 z={0.f,0.f,0.f,0.f}; accS[i][j]=z; }
    #pragma unroll
    for(int half=0; half<2; half++){
      bf16x8 bf[2];
      #pragma unroll
      for(int j=0;j<2;j++)
        bf[j] = *(const bf16x8*)&Ks[half*2048 + (wnS + j*16 + r16)*32 + q*8];
      #pragma unroll
      for(int i=0;i<2;i++)
        #pragma unroll
        for(int j=0;j<2;j++)
          accS[i][j] = __builtin_amdgcn_mfma_f32_16x16x32_bf16(qf[half][i], bf[j], accS[i][j], 0,0,0);
    }
    // exp, row-sums, write P (bf16) to LDS in [m][k] layout
    #pragma unroll
    for(int i=0;i<2;i++)
      #pragma unroll
      for(int j=0;j<2;j++)
        #pragma unroll
        for(int r=0;r<4;r++){
          const float p = __expf(accS[i][j][r] * 0.125f);
          ps[i][r] += p;
          Ps[(size_t)(wm + i*16 + q*4 + r)*PSTR + wnS + j*16 + r16] = f2bf(p);
        }
    __syncthreads();

    // O += P.V  (wave tile 32 q x 32 d, K=64)
    #pragma unroll
    for(int ks=0; ks<2; ks++){
      bf16x8 ap[2], bp[2];
      #pragma unroll
      for(int i=0;i<2;i++)
        ap[i] = *(const bf16x8*)&Ps[(size_t)(wm + i*16 + r16)*PSTR + ks*32 + q*8];
      #pragma unroll
      for(int j=0;j<2;j++)
        bp[j] = *(const bf16x8*)&Vt[(size_t)(wnO + j*16 + r16)*VSTR + ks*32 + q*8];
      #pragma unroll
      for(int i=0;i<2;i++)
        #pragma unroll
        for(int j=0;j<2;j++)
          acc_o[i][j] = __builtin_amdgcn_mfma_f32_16x16x32_bf16(ap[i], bp[j], acc_o[i][j], 0,0,0);
    }
  }

  // reduce ps across the 16 col-lanes of each quad
  #pragma unroll
  for(int i=0;i<2;i++)
    #pragma unroll
    for(int r=0;r<4;r++){
      float v = ps[i][r];
      v += __shfl_xor(v, 1, 64);
      v += __shfl_xor(v, 2, 64);
      v += __shfl_xor(v, 4, 64);
      v += __shfl_xor(v, 8, 64);
      ps[i][r] = v;
    }
  if(r16 == 0){
    #pragma unroll
    for(int i=0;i<2;i++)
      #pragma unroll
      for(int r=0;r<4;r++)
        lsump[w & 1][wm + i*16 + q*4 + r] = ps[i][r];
  }
  __syncthreads();

  // epilogue: normalize and store
  #pragma unroll
  for(int i=0;i<2;i++)
    #pragma unroll
    for(int r=0;r<4;r++){
      const int row = wm + i*16 + q*4 + r;
      const float inv = 1.0f / (lsump[0][row] + lsump[1][row]);
      #pragma unroll
      for(int j=0;j<2;j++){
        const int col = h*64 + wnO + j*16 + r16;
        out[(size_t)(b*Ssz + q0 + row)*Esz + col] = f2bf(acc_o[i][j][r] * inv);
      }
    }
}

// ---------------------------------------------------------------------------
// Row LayerNorm over E=1024: bf16 X -> bf16 Y (FIN=0) or fp32 direct to the
// final output (FIN=1). Thinking-path only: early-exit where modes[batch]==0.
// ---------------------------------------------------------------------------
template<int FIN>
__global__ __launch_bounds__(256)
void ln_kernel(const u16* __restrict__ X, const float* __restrict__ G,
               const float* __restrict__ Bi, u16* __restrict__ Y,
               const float* __restrict__ modes, float* __restrict__ outp)
{
  const int row = blockIdx.x;
  if(modes[row >> 10] == 0.0f) return;
  const int tid = threadIdx.x;
  const int wave = tid >> 6, lane = tid & 63;

  uint2 u = ((const uint2*)(X + (size_t)row*Esz))[tid];
  float x0,x1,x2,x3;
  unpack2(u.x, x0, x1); unpack2(u.y, x2, x3);
  float s  = x0+x1+x2+x3;
  float ss = x0*x0 + x1*x1 + x2*x2 + x3*x3;
  #pragma unroll
  for(int off=32; off; off>>=1){
    s  += __shfl_down(s,  off, 64);
    ss += __shfl_down(ss, off, 64);
  }
  __shared__ float rs[4], rss[4], bc[2];
  if(lane == 0){ rs[wave] = s; rss[wave] = ss; }
  __syncthreads();
  if(tid == 0){
    float S  = rs[0]+rs[1]+rs[2]+rs[3];
    float SS = rss[0]+rss[1]+rss[2]+rss[3];
    float mu  = S * (1.0f/1024.0f);
    float var = SS * (1.0f/1024.0f) - mu*mu;
    bc[0] = mu; bc[1] = 1.0f/sqrtf(var + 1e-5f);
  }
  __syncthreads();
  const float mu = bc[0], inv = bc[1];
  float4 g4 = ((const float4*)G)[tid];
  float4 b4 = ((const float4*)Bi)[tid];
  if(FIN){
    float4 o;
    o.x = (x0-mu)*inv*g4.x + b4.x;
    o.y = (x1-mu)*inv*g4.y + b4.y;
    o.z = (x2-mu)*inv*g4.z + b4.z;
    o.w = (x3-mu)*inv*g4.w + b4.w;
    ((float4*)(outp + (size_t)row*Esz))[tid] = o;
  } else {
    uint2 w;
    w.x = pack2((x0-mu)*inv*g4.x + b4.x, (x1-mu)*inv*g4.y + b4.y);
    w.y = pack2((x2-mu)*inv*g4.z + b4.z, (x3-mu)*inv*g4.w + b4.w);
    ((uint2*)(Y + (size_t)row*Esz))[tid] = w;
  }
}

// ---------------------------------------------------------------------------
// Complexity-estimator path — fp32 so routing matches the np reference
// ---------------------------------------------------------------------------
__global__ __launch_bounds__(256)
void pool1_kernel(const float* __restrict__ x, float* __restrict__ part)
{
  const int b = blockIdx.x, tc = blockIdx.y;
  const int e4 = threadIdx.x;
  const float* p = x + (size_t)(b*Ssz + tc*32)*Esz + e4*4;
  float4 s = {0.f,0.f,0.f,0.f};
  for(int t=0; t<32; t++){
    float4 v = *(const float4*)(p + (size_t)t*Esz);
    s.x += v.x; s.y += v.y; s.z += v.z; s.w += v.w;
  }
  ((float4*)(part + (size_t)(b*32 + tc)*Esz))[e4] = s;
}

__global__ void ce1_kernel(const float* __restrict__ part, const float* __restrict__ w1,
                           const float* __restrict__ b1, float* __restrict__ hbuf)
{
  __shared__ float pl[1024];
  const int b = blockIdx.x, n = threadIdx.x;
  for(int i = threadIdx.x; i < 1024; i += 256){
    float s = 0.f;
    for(int tc=0; tc<32; tc++) s += part[(size_t)(b*32 + tc)*Esz + i];
    pl[i] = s * (1.0f/1024.0f);
  }
  __syncthreads();
  const float* wr = w1 + (size_t)n*1024;
  float s = 0.f;
  for(int k=0; k<1024; k++) s += pl[k]*wr[k];
  s += b1[n];
  hbuf[b*256 + n] = fmaxf(s, 0.f);
}

__global__ void ce2_kernel(const float* __restrict__ hbuf, const float* __restrict__ w2,
                           const float* __restrict__ b2, float* __restrict__ modes,
                           float* __restrict__ outp)
{
  const int tid = threadIdx.x;
  const int b = tid >> 5, i = tid & 31;
  float s = 0.f;
  for(int k=i; k<256; k+=32) s += hbuf[b*256 + k] * w2[k];
  #pragma unroll
  for(int off=16; off; off>>=1) s += __shfl_down(s, off, 32);
  __shared__ float md[8];
  if(i == 0){
    const float logit = s + b2[0];
    const float prob = 1.0f/(1.0f + expf(-logit));
    const float m = prob > 0.5f ? 1.0f : 0.0f;
    modes[b] = m; md[b] = m;
    outp[OUT_PROBS + b] = prob;
    outp[OUT_MODE  + b] = m;
  }
  __syncthreads();
  if(tid == 0){
    float acc = 0.f;
    for(int k=0;k<8;k++) acc += md[k];
    outp[OUT_MEAN] = acc * 0.125f;
  }
}

// ---------------------------------------------------------------------------
extern "C" void kernel_launch(void* const* d_in, const int* in_sizes, int n_in,
                              void* d_out, int out_size, void* d_ws, size_t ws_size,
                              hipStream_t stream)
{
  const float* x      = (const float*)d_in[0];
  const float* w_in   = (const float*)d_in[1];
  const float* w_out  = (const float*)d_in[2];
  const float* ffn_w1 = (const float*)d_in[3];
  const float* ffn_w2 = (const float*)d_in[4];
  const float* ln1_g  = (const float*)d_in[5];
  const float* ln1_b  = (const float*)d_in[6];
  const float* ln2_g  = (const float*)d_in[7];
  const float* ln2_b  = (const float*)d_in[8];
  const float* ce_w1  = (const float*)d_in[9];
  const float* ce_b1  = (const float*)d_in[10];
  const float* ce_w2  = (const float*)d_in[11];
  const float* ce_b2  = (const float*)d_in[12];
  const float* fast_w = (const float*)d_in[13];
  float* out = (float*)d_out;

  // workspace layout (u16 units unless noted)
  u16* x_bf     = (u16*)d_ws;                          // 8192*1024
  u16* w_in_bf  = x_bf    + (size_t)8192*1024;
  u16* w_out_bf = w_in_bf + (size_t)2*3072*1024;
  u16* ffn1_bf  = w_out_bf+ (size_t)2*1024*1024;
  u16* ffn2_bf  = ffn1_bf + (size_t)2*4096*1024;
  u16* fast_bf  = ffn2_bf + (size_t)2*1024*4096;
  u16* big      = fast_bf + (size_t)1024*1024;         // 8192*4096 (qkv/hmid union)
  u16* attn     = big     + (size_t)8192*4096;
  u16* resid    = attn    + (size_t)8192*1024;
  u16* bufA     = resid   + (size_t)8192*1024;
  u16* bufB     = bufA    + (size_t)8192*1024;
  float* part   = (float*)(bufB + (size_t)8192*1024);  // 8*32*1024
  float* hbuf   = part + (size_t)8*32*1024;            // 2048
  float* modes  = hbuf + 2048;                         // 8
  const size_t need = (size_t)((char*)(modes + 8) - (char*)d_ws);
  if(ws_size < need) return;

  u16* qkv  = big;
  u16* hmid = big;

  // single-launch fp32 -> bf16 of all six tensors (8-elem units)
  {
    F2B p;
    p.s[0]=x;      p.d[0]=x_bf;     unsigned n0c = 8192u*1024u/8u;
    p.s[1]=w_in;   p.d[1]=w_in_bf;  unsigned n1c = 2u*3072u*1024u/8u;
    p.s[2]=w_out;  p.d[2]=w_out_bf; unsigned n2c = 2u*1024u*1024u/8u;
    p.s[3]=ffn_w1; p.d[3]=ffn1_bf;  unsigned n3c = 2u*4096u*1024u/8u;
    p.s[4]=ffn_w2; p.d[4]=ffn2_bf;  unsigned n4c = 2u*4096u*1024u/8u;
    p.s[5]=fast_w; p.d[5]=fast_bf;  unsigned n5c = 1024u*1024u/8u;
    p.end[0]=n0c; p.end[1]=p.end[0]+n1c; p.end[2]=p.end[1]+n2c;
    p.end[3]=p.end[2]+n3c; p.end[4]=p.end[3]+n4c; p.end[5]=p.end[4]+n5c;
    f2b_multi<<<p.end[5]/256, 256, 0, stream>>>(p);
  }

  pool1_kernel<<<dim3(8,32), 256, 0, stream>>>(x, part);
  ce1_kernel<<<8, 256, 0, stream>>>(part, ce_w1, ce_b1, hbuf);
  ce2_kernel<<<1, 256, 0, stream>>>(hbuf, ce_w2, ce_b2, modes, out);

  const u16* t = x_bf;
  for(int l=0; l<2; l++){
    gemm_bt<0,1><<<dim3(64,24), 256, 0, stream>>>(t, w_in_bf + (size_t)l*3072*1024, qkv, nullptr, modes, 3072, 1024);
    attn_kernel<<<2048, 256, 0, stream>>>(qkv, attn, modes);
    gemm_bt<1,1><<<dim3(64, 8), 256, 0, stream>>>(attn, w_out_bf + (size_t)l*1024*1024, resid, t, modes, 1024, 1024);
    ln_kernel<0><<<8192, 256, 0, stream>>>(resid, ln1_g + l*1024, ln1_b + l*1024, bufA, modes, nullptr);
    gemm_bt<2,1><<<dim3(64,32), 256, 0, stream>>>(bufA, ffn1_bf + (size_t)l*4096*1024, hmid, nullptr, modes, 4096, 1024);
    gemm_bt<1,1><<<dim3(64, 8), 256, 0, stream>>>(hmid, ffn2_bf + (size_t)l*1024*4096, resid, bufA, modes, 1024, 4096);
    if(l == 0)
      ln_kernel<0><<<8192, 256, 0, stream>>>(resid, ln2_g + l*1024, ln2_b + l*1024, bufB, modes, nullptr);
    else
      ln_kernel<1><<<8192, 256, 0, stream>>>(resid, ln2_g + l*1024, ln2_b + l*1024, nullptr, modes, out);
    t = bufB;
  }

  // fast path (fp32 gelu) into out for mode=0 batches only
  gemm_bt<3,2><<<dim3(64, 8), 256, 0, stream>>>(x_bf, fast_bf, out, nullptr, modes, 1024, 1024);
}

// Round 7
// 891.486 us; speedup vs baseline: 1.1060x; 1.1060x over previous
//
#include <hip/hip_runtime.h>
#include <cstdint>
#include <cstddef>

// Problem constants (fp32 in / fp32 out; bf16 internal compute, 2% tolerance)
#define Bsz 8
#define Ssz 1024
#define Esz 1024
#define Hn  16
#define Dh  64
#define OUT_PROBS 8388608
#define OUT_MODE  8388616
#define OUT_MEAN  8388624

typedef unsigned short u16;
typedef __attribute__((ext_vector_type(8)))  __bf16 bf16x8;
typedef __attribute__((ext_vector_type(4)))  float  floatx4;

__device__ __forceinline__ float bf2f(u16 u){ return __uint_as_float(((unsigned)u)<<16); }
__device__ __forceinline__ u16 f2bf(float f){
  unsigned u = __float_as_uint(f);
  u += 0x7fffu + ((u>>16)&1u);            // RNE
  return (u16)(u>>16);
}
__device__ __forceinline__ void unpack2(unsigned u, float& lo, float& hi){
  lo = __uint_as_float(u<<16);
  hi = __uint_as_float(u & 0xffff0000u);
}
__device__ __forceinline__ unsigned pack2(float lo, float hi){
  return (unsigned)f2bf(lo) | ((unsigned)f2bf(hi)<<16);
}
__device__ __forceinline__ void async16(const void* g, void* l){
  __builtin_amdgcn_global_load_lds((const __attribute__((address_space(1))) void*)g,
                                   (__attribute__((address_space(3))) void*)l, 16, 0, 0);
}
// tanh-form gelu: |err vs exact erf-gelu| <~1e-3, ~9 VALU inst (vs erff ~20)
__device__ __forceinline__ float gelu_fast(float x){
  const float x2 = x*x;
  const float y  = x * fmaf(0.0356774081f, x2, 0.7978845608f);  // sqrt(2/pi)*(x+0.044715x^3)
  const float e  = __expf(2.0f*y);
  const float t  = 1.0f - 2.0f/(e + 1.0f);                      // tanh(y)
  const float h  = 0.5f*x;
  return fmaf(h, t, h);
}

// ---------------------------------------------------------------------------
// fp32 -> bf16 conversion, all six tensors in one launch (8 elems/thread)
// ---------------------------------------------------------------------------
struct F2B {
  const float* s[6];
  u16* d[6];
  unsigned end[6];   // cumulative region ends, 8-elem units
};

__global__ __launch_bounds__(256)
void f2b_multi(F2B p)
{
  const unsigned i = blockIdx.x*256 + threadIdx.x;
  int k = 0;
  #pragma unroll
  for(int t=0; t<5; t++) if(i >= p.end[t]) k = t+1;
  const unsigned j = i - (k ? p.end[k-1] : 0);
  float4 a = ((const float4*)p.s[k])[2*j];
  float4 b = ((const float4*)p.s[k])[2*j+1];
  uint4 w;
  w.x = pack2(a.x, a.y); w.y = pack2(a.z, a.w);
  w.z = pack2(b.x, b.y); w.w = pack2(b.z, b.w);
  ((uint4*)p.d[k])[j] = w;
}

// ---------------------------------------------------------------------------
// GEMM: C[M,N] = A[M,K] @ W[N,K]^T, bf16 in, fp32 accum.
// BK=64 K-loop, two 128x32 LDS buffers per operand (64B row stride — the
// 16x16x32 fragment-read pattern is 2-way bank-aliased = free; the 32x32x16
// shape tripled SQ_LDS_BANK_CONFLICT and regressed 16% — round 6 post-mortem).
// EPI: 0 plain bf16; 1 bf16 + residual(bf16 R); 2 bf16 gelu; 3 f32 gelu
// SKIP: 1 = run only where modes[batch]!=0 (thinking); 2 = only modes==0 (fast)
// ---------------------------------------------------------------------------
template<int EPI, int SKIP>
__global__ __launch_bounds__(256, 2)
void gemm_bt(const u16* __restrict__ A, const u16* __restrict__ W,
             void* __restrict__ Cv, const u16* __restrict__ R,
             const float* __restrict__ modes, int N, int K)
{
  const int m0 = blockIdx.x * 128;
  if(SKIP == 1 && modes[m0 >> 10] == 0.0f) return;
  if(SKIP == 2 && modes[m0 >> 10] != 0.0f) return;

  __shared__ __align__(16) u16 AsLo[128*32];
  __shared__ __align__(16) u16 AsHi[128*32];
  __shared__ __align__(16) u16 BsLo[128*32];
  __shared__ __align__(16) u16 BsHi[128*32];

  const int tid  = threadIdx.x;
  const int wave = tid >> 6;
  const int lane = tid & 63;
  const int q    = lane >> 4;
  const int r16  = lane & 15;
  const int wm   = (wave >> 1) * 64;
  const int wn   = (wave & 1) * 64;
  const int n0   = blockIdx.y * 128;

  floatx4 acc[4][4];
  #pragma unroll
  for(int i=0;i<4;i++)
    #pragma unroll
    for(int j=0;j<4;j++){ floatx4 z = {0.f,0.f,0.f,0.f}; acc[i][j] = z; }

  const int row0 = tid >> 2;
  const int kc   = (tid & 3) * 8;

  const u16* pA0 = A + (size_t)(m0 + row0)*K + kc;
  const u16* pA1 = pA0 + (size_t)64*K;
  const u16* pB0 = W + (size_t)(n0 + row0)*K + kc;
  const u16* pB1 = pB0 + (size_t)64*K;

  for(int k0 = 0; k0 < K; k0 += 64, pA0 += 64, pA1 += 64, pB0 += 64, pB1 += 64){
    __syncthreads();
    async16(pA0,      AsLo + wave*512);
    async16(pA1,      AsLo + 2048 + wave*512);
    async16(pA0 + 32, AsHi + wave*512);
    async16(pA1 + 32, AsHi + 2048 + wave*512);
    async16(pB0,      BsLo + wave*512);
    async16(pB1,      BsLo + 2048 + wave*512);
    async16(pB0 + 32, BsHi + wave*512);
    async16(pB1 + 32, BsHi + 2048 + wave*512);
    __syncthreads();

    {
      bf16x8 af[4], bfr[4];
      #pragma unroll
      for(int i=0;i<4;i++){
        af[i]  = *(const bf16x8*)&AsLo[(wm + i*16 + r16)*32 + q*8];
        bfr[i] = *(const bf16x8*)&BsLo[(wn + i*16 + r16)*32 + q*8];
      }
      #pragma unroll
      for(int i=0;i<4;i++)
        #pragma unroll
        for(int j=0;j<4;j++)
          acc[i][j] = __builtin_amdgcn_mfma_f32_16x16x32_bf16(af[i], bfr[j], acc[i][j], 0, 0, 0);
    }
    {
      bf16x8 af[4], bfr[4];
      #pragma unroll
      for(int i=0;i<4;i++){
        af[i]  = *(const bf16x8*)&AsHi[(wm + i*16 + r16)*32 + q*8];
        bfr[i] = *(const bf16x8*)&BsHi[(wn + i*16 + r16)*32 + q*8];
      }
      #pragma unroll
      for(int i=0;i<4;i++)
        #pragma unroll
        for(int j=0;j<4;j++)
          acc[i][j] = __builtin_amdgcn_mfma_f32_16x16x32_bf16(af[i], bfr[j], acc[i][j], 0, 0, 0);
    }
  }

  // epilogue: C/D layout col=lane&15, row=quad*4+reg (m89/m91-verified)
  #pragma unroll
  for(int i=0;i<4;i++){
    const int row = m0 + wm + i*16 + q*4;
    #pragma unroll
    for(int j=0;j<4;j++){
      const int col = n0 + wn + j*16 + r16;
      #pragma unroll
      for(int r=0;r<4;r++){
        float v = acc[i][j][r];
        const size_t idx = (size_t)(row + r)*N + col;
        if(EPI == 1) v += bf2f(R[idx]);
        if(EPI == 2 || EPI == 3) v = gelu_fast(v);
        if(EPI == 3) ((float*)Cv)[idx] = v;
        else         ((u16*)Cv)[idx] = f2bf(v);
      }
    }
  }
}

// ---------------------------------------------------------------------------
// MFMA flash attention, v2. Block = 4 waves = 64-query tile of one (b,h).
// 16 KV chunks of 64 keys (34 KB LDS -> 4 blocks/CU). Q fragments hoisted to
// registers. Vt word-stride 34 and Ps stride 72 chosen so all LDS writes are
// <=2-way bank-aliased (free, m136). Early-exit for mode=0 batches.
// ---------------------------------------------------------------------------
#define VSTR 68    // u16 stride of Vt row (34 words; 8*34 % 32 = 16 -> 2-way)
#define PSTR 72    // u16 stride of Ps row (36 words)
__global__ __launch_bounds__(256, 4)
void attn_kernel(const u16* __restrict__ qkv, u16* __restrict__ out,
                 const float* __restrict__ modes)
{
  const int bh = blockIdx.x & 127;
  const int b  = bh >> 4;
  if(modes[b] == 0.0f) return;

  __shared__ __align__(16) u16 Qs[2*64*32];    // [half][row][32]
  __shared__ __align__(16) u16 Ks[2*64*32];    // [half][row][32]
  __shared__ __align__(16) u16 Vt[64*VSTR];    // [d][k] packed words
  __shared__ __align__(16) u16 Ps[64*PSTR];    // [m][k]
  __shared__ float lsump[2][64];

  const int tid = threadIdx.x;
  const int w   = tid >> 6;
  const int lane= tid & 63;
  const int q   = lane >> 4;
  const int r16 = lane & 15;

  const int qt = blockIdx.x >> 7;
  const int h  = bh & 15;
  const int q0 = qt * 64;

  const u16* qbase = qkv + (size_t)(b*Ssz)*3072;

  const int sr = tid >> 2;          // staging row 0..63
  const int sc = (tid & 3) * 8;     // staging col offset

  // stage Q tile (64x64) -> [half][64][32]
  #pragma unroll
  for(int half=0; half<2; half++)
    async16(qbase + (size_t)(q0 + sr)*3072 + h*64 + half*32 + sc,
            &Qs[half*2048 + w*512]);
  __syncthreads();

  const int wm  = (w >> 1) * 32;   // query-row offset
  const int wnS = (w & 1) * 32;    // key-col offset in S
  const int wnO = (w & 1) * 32;    // d-col offset in O

  // hoist Q fragments (chunk-invariant)
  bf16x8 qf[2][2];
  #pragma unroll
  for(int half=0; half<2; half++)
    #pragma unroll
    for(int i=0;i<2;i++)
      qf[half][i] = *(const bf16x8*)&Qs[half*2048 + (wm + i*16 + r16)*32 + q*8];

  floatx4 acc_o[2][2];
  #pragma unroll
  for(int i=0;i<2;i++)
    #pragma unroll
    for(int j=0;j<2;j++){ floatx4 z={0.f,0.f,0.f,0.f}; acc_o[i][j]=z; }
  float ps[2][4] = {{0.f,0.f,0.f,0.f},{0.f,0.f,0.f,0.f}};

  const int kp = tid & 31;          // key-pair for Vt staging
  const int dg = tid >> 5;          // d-group 0..7

  for(int ck=0; ck<16; ck++){
    const int k0 = ck*64;
    __syncthreads();   // prior-chunk Ks/Vt/Ps reads complete
    // stage K (64x64) -> [half][64][32]
    #pragma unroll
    for(int half=0; half<2; half++)
      async16(qbase + (size_t)(k0 + sr)*3072 + 1024 + h*64 + half*32 + sc,
              &Ks[half*2048 + w*512]);
    // stage V transposed: Vt[d][k], keys packed in pairs per word
    {
      const uint4 va = *(const uint4*)(qbase + (size_t)(k0 + 2*kp    )*3072 + 2048 + h*64 + dg*8);
      const uint4 vb = *(const uint4*)(qbase + (size_t)(k0 + 2*kp + 1)*3072 + 2048 + h*64 + dg*8);
      unsigned wa[4] = {va.x,va.y,va.z,va.w};
      unsigned wb[4] = {vb.x,vb.y,vb.z,vb.w};
      unsigned* vt32 = (unsigned*)Vt;
      #pragma unroll
      for(int u=0; u<4; u++){
        const int d0 = dg*8 + 2*u;
        vt32[(size_t)d0*34 + kp]     = (wa[u] & 0xffffu) | (wb[u] << 16);
        vt32[(size_t)(d0+1)*34 + kp] = (wa[u] >> 16) | (wb[u] & 0xffff0000u);
      }
    }
    __syncthreads();

    // S = Q.K^T  (wave tile 32 q x 32 keys, K=64)
    floatx4 accS[2][2];
    #pragma unroll
    for(int i=0;i<2;i++)
      #pragma unroll
      for(int j=0;j<2;j++){ floatx4 z={0.f,0.f,0.f,0.f}; accS[i][j]=z; }
    #pragma unroll
    for(int half=0; half<2; half++){
      bf16x8 bf[2];
      #pragma unroll
      for(int j=0;j<2;j++)
        bf[j] = *(const bf16x8*)&Ks[half*2048 + (wnS + j*16 + r16)*32 + q*8];
      #pragma unroll
      for(int i=0;i<2;i++)
        #pragma unroll
        for(int j=0;j<2;j++)
          accS[i][j] = __builtin_amdgcn_mfma_f32_16x16x32_bf16(qf[half][i], bf[j], accS[i][j], 0,0,0);
    }
    // exp, row-sums, write P (bf16) to LDS in [m][k] layout
    #pragma unroll
    for(int i=0;i<2;i++)
      #pragma unroll
      for(int j=0;j<2;j++)
        #pragma unroll
        for(int r=0;r<4;r++){
          const float p = __expf(accS[i][j][r] * 0.125f);
          ps[i][r] += p;
          Ps[(size_t)(wm + i*16 + q*4 + r)*PSTR + wnS + j*16 + r16] = f2bf(p);
        }
    __syncthreads();

    // O += P.V  (wave tile 32 q x 32 d, K=64)
    #pragma unroll
    for(int ks=0; ks<2; ks++){
      bf16x8 ap[2], bp[2];
      #pragma unroll
      for(int i=0;i<2;i++)
        ap[i] = *(const bf16x8*)&Ps[(size_t)(wm + i*16 + r16)*PSTR + ks*32 + q*8];
      #pragma unroll
      for(int j=0;j<2;j++)
        bp[j] = *(const bf16x8*)&Vt[(size_t)(wnO + j*16 + r16)*VSTR + ks*32 + q*8];
      #pragma unroll
      for(int i=0;i<2;i++)
        #pragma unroll
        for(int j=0;j<2;j++)
          acc_o[i][j] = __builtin_amdgcn_mfma_f32_16x16x32_bf16(ap[i], bp[j], acc_o[i][j], 0,0,0);
    }
  }

  // reduce ps across the 16 col-lanes of each quad
  #pragma unroll
  for(int i=0;i<2;i++)
    #pragma unroll
    for(int r=0;r<4;r++){
      float v = ps[i][r];
      v += __shfl_xor(v, 1, 64);
      v += __shfl_xor(v, 2, 64);
      v += __shfl_xor(v, 4, 64);
      v += __shfl_xor(v, 8, 64);
      ps[i][r] = v;
    }
  if(r16 == 0){
    #pragma unroll
    for(int i=0;i<2;i++)
      #pragma unroll
      for(int r=0;r<4;r++)
        lsump[w & 1][wm + i*16 + q*4 + r] = ps[i][r];
  }
  __syncthreads();

  // epilogue: normalize and store
  #pragma unroll
  for(int i=0;i<2;i++)
    #pragma unroll
    for(int r=0;r<4;r++){
      const int row = wm + i*16 + q*4 + r;
      const float inv = 1.0f / (lsump[0][row] + lsump[1][row]);
      #pragma unroll
      for(int j=0;j<2;j++){
        const int col = h*64 + wnO + j*16 + r16;
        out[(size_t)(b*Ssz + q0 + row)*Esz + col] = f2bf(acc_o[i][j][r] * inv);
      }
    }
}

// ---------------------------------------------------------------------------
// Row LayerNorm over E=1024: bf16 X -> bf16 Y (FIN=0) or fp32 direct to the
// final output (FIN=1). Thinking-path only: early-exit where modes[batch]==0.
// ---------------------------------------------------------------------------
template<int FIN>
__global__ __launch_bounds__(256)
void ln_kernel(const u16* __restrict__ X, const float* __restrict__ G,
               const float* __restrict__ Bi, u16* __restrict__ Y,
               const float* __restrict__ modes, float* __restrict__ outp)
{
  const int row = blockIdx.x;
  if(modes[row >> 10] == 0.0f) return;
  const int tid = threadIdx.x;
  const int wave = tid >> 6, lane = tid & 63;

  uint2 u = ((const uint2*)(X + (size_t)row*Esz))[tid];
  float x0,x1,x2,x3;
  unpack2(u.x, x0, x1); unpack2(u.y, x2, x3);
  float s  = x0+x1+x2+x3;
  float ss = x0*x0 + x1*x1 + x2*x2 + x3*x3;
  #pragma unroll
  for(int off=32; off; off>>=1){
    s  += __shfl_down(s,  off, 64);
    ss += __shfl_down(ss, off, 64);
  }
  __shared__ float rs[4], rss[4], bc[2];
  if(lane == 0){ rs[wave] = s; rss[wave] = ss; }
  __syncthreads();
  if(tid == 0){
    float S  = rs[0]+rs[1]+rs[2]+rs[3];
    float SS = rss[0]+rss[1]+rss[2]+rss[3];
    float mu  = S * (1.0f/1024.0f);
    float var = SS * (1.0f/1024.0f) - mu*mu;
    bc[0] = mu; bc[1] = 1.0f/sqrtf(var + 1e-5f);
  }
  __syncthreads();
  const float mu = bc[0], inv = bc[1];
  float4 g4 = ((const float4*)G)[tid];
  float4 b4 = ((const float4*)Bi)[tid];
  if(FIN){
    float4 o;
    o.x = (x0-mu)*inv*g4.x + b4.x;
    o.y = (x1-mu)*inv*g4.y + b4.y;
    o.z = (x2-mu)*inv*g4.z + b4.z;
    o.w = (x3-mu)*inv*g4.w + b4.w;
    ((float4*)(outp + (size_t)row*Esz))[tid] = o;
  } else {
    uint2 w;
    w.x = pack2((x0-mu)*inv*g4.x + b4.x, (x1-mu)*inv*g4.y + b4.y);
    w.y = pack2((x2-mu)*inv*g4.z + b4.z, (x3-mu)*inv*g4.w + b4.w);
    ((uint2*)(Y + (size_t)row*Esz))[tid] = w;
  }
}

// ---------------------------------------------------------------------------
// Complexity-estimator path — fp32 so routing matches the np reference
// ---------------------------------------------------------------------------
__global__ __launch_bounds__(256)
void pool1_kernel(const float* __restrict__ x, float* __restrict__ part)
{
  const int b = blockIdx.x, tc = blockIdx.y;
  const int e4 = threadIdx.x;
  const float* p = x + (size_t)(b*Ssz + tc*32)*Esz + e4*4;
  float4 s = {0.f,0.f,0.f,0.f};
  for(int t=0; t<32; t++){
    float4 v = *(const float4*)(p + (size_t)t*Esz);
    s.x += v.x; s.y += v.y; s.z += v.z; s.w += v.w;
  }
  ((float4*)(part + (size_t)(b*32 + tc)*Esz))[e4] = s;
}

__global__ void ce1_kernel(const float* __restrict__ part, const float* __restrict__ w1,
                           const float* __restrict__ b1, float* __restrict__ hbuf)
{
  __shared__ float pl[1024];
  const int b = blockIdx.x, n = threadIdx.x;
  for(int i = threadIdx.x; i < 1024; i += 256){
    float s = 0.f;
    for(int tc=0; tc<32; tc++) s += part[(size_t)(b*32 + tc)*Esz + i];
    pl[i] = s * (1.0f/1024.0f);
  }
  __syncthreads();
  const float* wr = w1 + (size_t)n*1024;
  float s = 0.f;
  for(int k=0; k<1024; k++) s += pl[k]*wr[k];
  s += b1[n];
  hbuf[b*256 + n] = fmaxf(s, 0.f);
}

__global__ void ce2_kernel(const float* __restrict__ hbuf, const float* __restrict__ w2,
                           const float* __restrict__ b2, float* __restrict__ modes,
                           float* __restrict__ outp)
{
  const int tid = threadIdx.x;
  const int b = tid >> 5, i = tid & 31;
  float s = 0.f;
  for(int k=i; k<256; k+=32) s += hbuf[b*256 + k] * w2[k];
  #pragma unroll
  for(int off=16; off; off>>=1) s += __shfl_down(s, off, 32);
  __shared__ float md[8];
  if(i == 0){
    const float logit = s + b2[0];
    const float prob = 1.0f/(1.0f + expf(-logit));
    const float m = prob > 0.5f ? 1.0f : 0.0f;
    modes[b] = m; md[b] = m;
    outp[OUT_PROBS + b] = prob;
    outp[OUT_MODE  + b] = m;
  }
  __syncthreads();
  if(tid == 0){
    float acc = 0.f;
    for(int k=0;k<8;k++) acc += md[k];
    outp[OUT_MEAN] = acc * 0.125f;
  }
}

// ---------------------------------------------------------------------------
extern "C" void kernel_launch(void* const* d_in, const int* in_sizes, int n_in,
                              void* d_out, int out_size, void* d_ws, size_t ws_size,
                              hipStream_t stream)
{
  const float* x      = (const float*)d_in[0];
  const float* w_in   = (const float*)d_in[1];
  const float* w_out  = (const float*)d_in[2];
  const float* ffn_w1 = (const float*)d_in[3];
  const float* ffn_w2 = (const float*)d_in[4];
  const float* ln1_g  = (const float*)d_in[5];
  const float* ln1_b  = (const float*)d_in[6];
  const float* ln2_g  = (const float*)d_in[7];
  const float* ln2_b  = (const float*)d_in[8];
  const float* ce_w1  = (const float*)d_in[9];
  const float* ce_b1  = (const float*)d_in[10];
  const float* ce_w2  = (const float*)d_in[11];
  const float* ce_b2  = (const float*)d_in[12];
  const float* fast_w = (const float*)d_in[13];
  float* out = (float*)d_out;

  // workspace layout (u16 units unless noted)
  u16* x_bf     = (u16*)d_ws;                          // 8192*1024
  u16* w_in_bf  = x_bf    + (size_t)8192*1024;
  u16* w_out_bf = w_in_bf + (size_t)2*3072*1024;
  u16* ffn1_bf  = w_out_bf+ (size_t)2*1024*1024;
  u16* ffn2_bf  = ffn1_bf + (size_t)2*4096*1024;
  u16* fast_bf  = ffn2_bf + (size_t)2*1024*4096;
  u16* big      = fast_bf + (size_t)1024*1024;         // 8192*4096 (qkv/hmid union)
  u16* attn     = big     + (size_t)8192*4096;
  u16* resid    = attn    + (size_t)8192*1024;
  u16* bufA     = resid   + (size_t)8192*1024;
  u16* bufB     = bufA    + (size_t)8192*1024;
  float* part   = (float*)(bufB + (size_t)8192*1024);  // 8*32*1024
  float* hbuf   = part + (size_t)8*32*1024;            // 2048
  float* modes  = hbuf + 2048;                         // 8
  const size_t need = (size_t)((char*)(modes + 8) - (char*)d_ws);
  if(ws_size < need) return;

  u16* qkv  = big;
  u16* hmid = big;

  // single-launch fp32 -> bf16 of all six tensors (8-elem units)
  {
    F2B p;
    p.s[0]=x;      p.d[0]=x_bf;     unsigned n0c = 8192u*1024u/8u;
    p.s[1]=w_in;   p.d[1]=w_in_bf;  unsigned n1c = 2u*3072u*1024u/8u;
    p.s[2]=w_out;  p.d[2]=w_out_bf; unsigned n2c = 2u*1024u*1024u/8u;
    p.s[3]=ffn_w1; p.d[3]=ffn1_bf;  unsigned n3c = 2u*4096u*1024u/8u;
    p.s[4]=ffn_w2; p.d[4]=ffn2_bf;  unsigned n4c = 2u*4096u*1024u/8u;
    p.s[5]=fast_w; p.d[5]=fast_bf;  unsigned n5c = 1024u*1024u/8u;
    p.end[0]=n0c; p.end[1]=p.end[0]+n1c; p.end[2]=p.end[1]+n2c;
    p.end[3]=p.end[2]+n3c; p.end[4]=p.end[3]+n4c; p.end[5]=p.end[4]+n5c;
    f2b_multi<<<p.end[5]/256, 256, 0, stream>>>(p);
  }

  pool1_kernel<<<dim3(8,32), 256, 0, stream>>>(x, part);
  ce1_kernel<<<8, 256, 0, stream>>>(part, ce_w1, ce_b1, hbuf);
  ce2_kernel<<<1, 256, 0, stream>>>(hbuf, ce_w2, ce_b2, modes, out);

  const u16* t = x_bf;
  for(int l=0; l<2; l++){
    gemm_bt<0,1><<<dim3(64,24), 256, 0, stream>>>(t, w_in_bf + (size_t)l*3072*1024, qkv, nullptr, modes, 3072, 1024);
    attn_kernel<<<2048, 256, 0, stream>>>(qkv, attn, modes);
    gemm_bt<1,1><<<dim3(64, 8), 256, 0, stream>>>(attn, w_out_bf + (size_t)l*1024*1024, resid, t, modes, 1024, 1024);
    ln_kernel<0><<<8192, 256, 0, stream>>>(resid, ln1_g + l*1024, ln1_b + l*1024, bufA, modes, nullptr);
    gemm_bt<2,1><<<dim3(64,32), 256, 0, stream>>>(bufA, ffn1_bf + (size_t)l*4096*1024, hmid, nullptr, modes, 4096, 1024);
    gemm_bt<1,1><<<dim3(64, 8), 256, 0, stream>>>(hmid, ffn2_bf + (size_t)l*1024*4096, resid, bufA, modes, 1024, 4096);
    if(l == 0)
      ln_kernel<0><<<8192, 256, 0, stream>>>(resid, ln2_g + l*1024, ln2_b + l*1024, bufB, modes, nullptr);
    else
      ln_kernel<1><<<8192, 256, 0, stream>>>(resid, ln2_g + l*1024, ln2_b + l*1024, nullptr, modes, out);
    t = bufB;
  }

  // fast path (fp32 gelu) into out for mode=0 batches only
  gemm_bt<3,2><<<dim3(64, 8), 256, 0, stream>>>(x_bf, fast_bf, out, nullptr, modes, 1024, 1024);
}